// Round 1
// baseline (133.904 us; speedup 1.0000x reference)
//
#include <hip/hip_runtime.h>
#include <hip/hip_bf16.h>

// Tucker: out[a,s,t] = sum_{f,e,g} act[a,f]*state[s,e]*core[f,e,g]*state[t,g]
// A=64, S=T=1024, E=G=64, F=32.
// Stage A: Wt[a][g][e] = sum_f act[a,f]*core[f,e,g]      (bf16, 512 KB)
// Stage S: state -> bf16                                  (128 KB)
// Stage B: U[a][s][g] = sum_e state[s,e]*W_a[e,g]         (NT GEMM vs Wt, bf16, 8 MB)
// Stage C: out[(a,s)][t] = sum_g U[(a,s)][g]*state[t,g]   (NT GEMM, fp32 out, 256 MiB)

typedef __attribute__((ext_vector_type(8))) __bf16 bf16x8;
typedef __attribute__((ext_vector_type(4))) float f32x4;

static __device__ __forceinline__ unsigned short f2bf(float x) {
    union { float f; unsigned int u; } c; c.f = x;
    unsigned int lsb = (c.u >> 16) & 1u;
    c.u += 0x7fffu + lsb;               // round-to-nearest-even
    return (unsigned short)(c.u >> 16);
}

// ---- Stage S: convert state (1024x64 fp32) to bf16 ----
__global__ void cvt_state_bf16(const float* __restrict__ s, unsigned short* __restrict__ sb) {
    int i = blockIdx.x * blockDim.x + threadIdx.x;   // 16384 float4s
    float4 v = reinterpret_cast<const float4*>(s)[i];
    union { unsigned short u[4]; unsigned long long ull; } r;
    r.u[0] = f2bf(v.x); r.u[1] = f2bf(v.y); r.u[2] = f2bf(v.z); r.u[3] = f2bf(v.w);
    reinterpret_cast<unsigned long long*>(sb)[i] = r.ull;
}

// ---- Stage A: Wt[a][g][e] = sum_f act[a*32+f] * core[(f*64+e)*64+g] ----
__global__ void build_wt(const float* __restrict__ act, const float* __restrict__ core,
                         unsigned short* __restrict__ wt) {
    int a = blockIdx.x;           // 64 blocks
    int t = threadIdx.x;          // 256 threads
    __shared__ float af[32];
    if (t < 32) af[t] = act[a * 32 + t];
    __syncthreads();
    for (int i = 0; i < 16; ++i) {
        int idx = t + i * 256;    // 4096 (e,g) pairs
        int e = idx >> 6, g = idx & 63;
        float acc = 0.f;
#pragma unroll
        for (int f = 0; f < 32; ++f)
            acc += af[f] * core[(f * 64 + e) * 64 + g];
        wt[a * 4096 + g * 64 + e] = f2bf(acc);   // store transposed (g,e)
    }
}

// ---- Stage B: U[a][s][g] = state(s,e) . Wt_a(g,e)^T  (NT GEMM, M=1024,N=64,K=64 per a) ----
__global__ __launch_bounds__(256) void gemm_u(const unsigned short* __restrict__ sb,
                                              const unsigned short* __restrict__ wt,
                                              unsigned short* __restrict__ u) {
    int bx = blockIdx.x;                  // 256 blocks: a(64) x stile(4)
    int a = bx >> 2, st = bx & 3;
    int wid = threadIdx.x >> 6, lane = threadIdx.x & 63;
    int r0 = st * 256 + wid * 64;         // 64 s-rows per wave
    int lr = lane & 15, lk = (lane >> 4) * 8;
    const unsigned short* wta = wt + a * 4096;

    f32x4 acc[4][4] = {};
    bf16x8 afr[4][2], bfr[4][2];
#pragma unroll
    for (int m = 0; m < 4; ++m)
#pragma unroll
        for (int kk = 0; kk < 2; ++kk)
            afr[m][kk] = *reinterpret_cast<const bf16x8*>(sb + (r0 + m * 16 + lr) * 64 + kk * 32 + lk);
#pragma unroll
    for (int n = 0; n < 4; ++n)
#pragma unroll
        for (int kk = 0; kk < 2; ++kk)
            bfr[n][kk] = *reinterpret_cast<const bf16x8*>(wta + (n * 16 + lr) * 64 + kk * 32 + lk);
#pragma unroll
    for (int kk = 0; kk < 2; ++kk)
#pragma unroll
        for (int m = 0; m < 4; ++m)
#pragma unroll
            for (int n = 0; n < 4; ++n)
                acc[m][n] = __builtin_amdgcn_mfma_f32_16x16x32_bf16(afr[m][kk], bfr[n][kk], acc[m][n], 0, 0, 0);

    int rr = (lane >> 4) * 4;
#pragma unroll
    for (int m = 0; m < 4; ++m)
#pragma unroll
        for (int n = 0; n < 4; ++n)
#pragma unroll
            for (int q = 0; q < 4; ++q) {
                int srow = r0 + m * 16 + rr + q;
                int g = n * 16 + lr;
                u[a * 65536 + srow * 64 + g] = f2bf(acc[m][n][q]);
            }
}

// ---- Stage C: out[(a,s)][t] = U((a,s),g) . state(t,g)^T  (NT GEMM, M=65536,N=1024,K=64) ----
__global__ __launch_bounds__(256) void gemm_out(const unsigned short* __restrict__ u,
                                                const unsigned short* __restrict__ sb,
                                                float* __restrict__ out) {
    int bx = blockIdx.x;                  // 4096 blocks: 512 mb x 8 nb
    int mb = bx >> 3, nb = bx & 7;        // consecutive blocks share the U tile (L2 reuse)
    int wid = threadIdx.x >> 6, lane = threadIdx.x & 63;
    int wr = wid >> 1, wc = wid & 1;      // 2x2 waves of 64x64
    int r0 = mb * 128 + wr * 64;
    int c0 = nb * 128 + wc * 64;
    int lr = lane & 15, lk = (lane >> 4) * 8;

    f32x4 acc[4][4] = {};
    bf16x8 afr[4][2], bfr[4][2];
#pragma unroll
    for (int m = 0; m < 4; ++m)
#pragma unroll
        for (int kk = 0; kk < 2; ++kk)
            afr[m][kk] = *reinterpret_cast<const bf16x8*>(u + (r0 + m * 16 + lr) * 64 + kk * 32 + lk);
#pragma unroll
    for (int n = 0; n < 4; ++n)
#pragma unroll
        for (int kk = 0; kk < 2; ++kk)
            bfr[n][kk] = *reinterpret_cast<const bf16x8*>(sb + (c0 + n * 16 + lr) * 64 + kk * 32 + lk);
#pragma unroll
    for (int kk = 0; kk < 2; ++kk)
#pragma unroll
        for (int m = 0; m < 4; ++m)
#pragma unroll
            for (int n = 0; n < 4; ++n)
                acc[m][n] = __builtin_amdgcn_mfma_f32_16x16x32_bf16(afr[m][kk], bfr[n][kk], acc[m][n], 0, 0, 0);

    int rr = (lane >> 4) * 4;
#pragma unroll
    for (int m = 0; m < 4; ++m)
#pragma unroll
        for (int q = 0; q < 4; ++q) {
            size_t row = (size_t)(r0 + m * 16 + rr + q);
            float* orow = out + row * 1024 + c0;
#pragma unroll
            for (int n = 0; n < 4; ++n)
                orow[n * 16 + lr] = acc[m][n][q];
        }
}

extern "C" void kernel_launch(void* const* d_in, const int* in_sizes, int n_in,
                              void* d_out, int out_size, void* d_ws, size_t ws_size,
                              hipStream_t stream) {
    const float* state = (const float*)d_in[0];   // 1024 x 64
    const float* act   = (const float*)d_in[1];   // 64 x 32
    const float* core  = (const float*)d_in[2];   // 32 x 64 x 64
    float* out = (float*)d_out;                   // 64 x 1024 x 1024

    unsigned short* sb = (unsigned short*)d_ws;   // state bf16: 65536 (128 KB)
    unsigned short* wt = sb + 65536;              // Wt bf16:   262144 (512 KB)
    unsigned short* u  = wt + 262144;             // U bf16:    4194304 (8 MB)

    cvt_state_bf16<<<64, 256, 0, stream>>>(state, sb);
    build_wt<<<64, 256, 0, stream>>>(act, core, wt);
    gemm_u<<<256, 256, 0, stream>>>(sb, wt, u);
    gemm_out<<<4096, 256, 0, stream>>>(u, sb, out);
}